// Round 1
// baseline (544.944 us; speedup 1.0000x reference)
//
#include <hip/hip_runtime.h>
#include <math.h>

#define VOCAB 27
#define EMB   32
#define HID   64
#define BATCH 4096
#define TLEN  256

__device__ __forceinline__ float bcast(float v, int lane) {
    return __int_as_float(__builtin_amdgcn_readlane(__float_as_int(v), lane));
}

__global__ __launch_bounds__(256, 2) void rnn_fused(
    const int*   __restrict__ X,      // (B,T)
    const float* __restrict__ emb_w,  // (27,32)
    const float* __restrict__ start,  // (1,64)
    const float* __restrict__ rnn_w,  // (64,96)  [:, :32]=Wx  [:, 32:]=Wh
    const float* __restrict__ rnn_b,  // (64)
    const float* __restrict__ lm_w,   // (27,64)
    const float* __restrict__ lm_b,   // (27)
    float*       __restrict__ out)    // (B,T,27)
{
    __shared__ float table[VOCAB][HID];  // xp table: rnn_b + Wx . emb_w[v]

    const int tid = threadIdx.x;

    // Build the 27x64 xproj lookup table once per block (collapses emb+xproj).
    for (int f = tid; f < VOCAB * HID; f += 256) {
        const int v = f / HID, i = f - v * HID;
        float s = rnn_b[i];
        #pragma unroll
        for (int e = 0; e < EMB; ++e)
            s += rnn_w[i * (EMB + HID) + e] * emb_w[v * EMB + e];
        table[v][i] = s;
    }
    __syncthreads();

    const int lane = tid & 63;
    const int wave = tid >> 6;
    const int b    = blockIdx.x * 4 + wave;

    // Per-lane register tiles: Wh row `lane`, lm_w row `lane` (clamped).
    float wh[HID];
    #pragma unroll
    for (int j = 0; j < HID; ++j)
        wh[j] = rnn_w[lane * (EMB + HID) + EMB + j];

    const int vv = (lane < VOCAB) ? lane : (VOCAB - 1);
    float lw[HID];
    #pragma unroll
    for (int j = 0; j < HID; ++j)
        lw[j] = lm_w[vv * HID + j];
    const float lb = lm_b[vv];

    // Preload this batch row of token ids: xi_k holds X[b][k*64 + lane].
    const int* Xb = X + (size_t)b * TLEN;
    const int xi0 = Xb[0 * 64 + lane];
    const int xi1 = Xb[1 * 64 + lane];
    const int xi2 = Xb[2 * 64 + lane];
    const int xi3 = Xb[3 * 64 + lane];

    float h = start[lane];                    // h_{-1}
    float* outb = out + (size_t)b * TLEN * VOCAB;

    // xp for t=0
    float xp = table[__builtin_amdgcn_readlane(xi0, 0)][lane];

    for (int t = 0; t < TLEN; ++t) {
        // Prefetch next step's xp (uniform token id via readlane -> SGPR base).
        const int tn  = (t + 1 < TLEN) ? (t + 1) : (TLEN - 1);
        const int xr  = (tn < 64) ? xi0 : (tn < 128) ? xi1 : (tn < 192) ? xi2 : xi3;
        const int idx = __builtin_amdgcn_readlane(xr, tn & 63);
        const float xp_next = table[idx][lane];

        // Broadcast h_{t-1}; accumulate recurrence (for h_t) and logits_{t-1}.
        float acc = xp;
        float lg  = lb;
        #pragma unroll
        for (int j = 0; j < HID; ++j) {
            const float hj = bcast(h, j);
            acc += wh[j] * hj;   // Wh[lane][j] * h_{t-1}[j]
            lg  += lw[j] * hj;   // lm_w[lane][j] * h_{t-1}[j]
        }
        if (t > 0 && lane < VOCAB)
            outb[(size_t)(t - 1) * VOCAB + lane] = lg;

        h  = tanhf(acc);         // h_t
        xp = xp_next;
    }

    // Final logits for t = T-1 from h_{T-1}.
    {
        float lg = lb;
        #pragma unroll
        for (int j = 0; j < HID; ++j) {
            const float hj = bcast(h, j);
            lg += lw[j] * hj;
        }
        if (lane < VOCAB)
            outb[(size_t)(TLEN - 1) * VOCAB + lane] = lg;
    }
}

extern "C" void kernel_launch(void* const* d_in, const int* in_sizes, int n_in,
                              void* d_out, int out_size, void* d_ws, size_t ws_size,
                              hipStream_t stream) {
    const int*   X     = (const int*)  d_in[0];
    const float* emb_w = (const float*)d_in[1];
    const float* start = (const float*)d_in[2];
    const float* rnn_w = (const float*)d_in[3];
    const float* rnn_b = (const float*)d_in[4];
    const float* lm_w  = (const float*)d_in[5];
    const float* lm_b  = (const float*)d_in[6];
    float*       out   = (float*)d_out;

    dim3 grid(BATCH / 4);   // 4 batch rows (waves) per 256-thread block
    dim3 block(256);
    rnn_fused<<<grid, block, 0, stream>>>(X, emb_w, start, rnn_w, rnn_b,
                                          lm_w, lm_b, out);
}